// Round 10
// baseline (48.347 us; speedup 1.0000x reference)
//
#include <hip/hip_runtime.h>
#include <hip/hip_bf16.h>

// Quantum layer: 4 qubits, 2 layers. Everything after the RY(x) encoding is a
// fixed unitary U (weights are batch-constant). Each output q is multilinear
// in (1, cos th_p, sin th_p) per qubit: 81 coefficients per output.
// qsetup (4 blocks) computes C as [4][27] float4 (triple + pad) into d_ws.
//
// Delivery-path ledger (all measured on this problem):
//   per-lane VMEM dword reload, 324/elem   ~20-22us  (R1/R4; VMEM-issue bound)
//   LDS broadcast                          ~52us     (R3)
//   scalar SMEM (any flavor)               ~42-55us  (R6/R7/R9: v_mov tax,
//                                                     lgkm serialization)
//   27-wide asm VGPR batch                 220us     (R8: forced liveness->spill)
// This round: per-lane float4 VMEM loads (compiler CANNOT scalarize because
// the address offset is laundered through a volatile asm into a VGPR), plain
// C++ loads so RA schedules them liveness-aware, reused across EPT=4 elements
// -> 27 VMEM instrs/element (12x fewer than R1/R4's 324).

__global__ __launch_bounds__(256) void qsetup(const float* __restrict__ w,
                                              float* __restrict__ C) {
    __shared__ float Ur[16][16];   // [row k][col j]
    __shared__ float Ui[16][16];
    __shared__ float M[16][16];
    const int q = blockIdx.x;      // output qubit 0..3
    const int tid = threadIdx.x;

    // ---- step 1: threads 0..15 each simulate one basis column of U ----
    if (tid < 16) {
        float re[16], im[16];
#pragma unroll
        for (int i = 0; i < 16; ++i) { re[i] = (i == tid) ? 1.0f : 0.0f; im[i] = 0.0f; }

#pragma unroll
        for (int ly = 0; ly < 2; ++ly) {
#pragma unroll
            for (int qq = 0; qq < 4; ++qq) {
                const int mm = 8 >> qq;
                float th, c, s;
                // RX(w[ly][qq][0])
                th = w[(ly * 4 + qq) * 3 + 0] * 0.5f; c = __cosf(th); s = __sinf(th);
#pragma unroll
                for (int i = 0; i < 16; ++i) if (!(i & mm)) {
                    const int j = i | mm;
                    float r0 = re[i], i0 = im[i], r1 = re[j], i1 = im[j];
                    re[i] = c * r0 + s * i1;  im[i] = c * i0 - s * r1;
                    re[j] = s * i0 + c * r1;  im[j] = -s * r0 + c * i1;
                }
                // RY(w[ly][qq][1])
                th = w[(ly * 4 + qq) * 3 + 1] * 0.5f; c = __cosf(th); s = __sinf(th);
#pragma unroll
                for (int i = 0; i < 16; ++i) if (!(i & mm)) {
                    const int j = i | mm;
                    float r0 = re[i], i0 = im[i], r1 = re[j], i1 = im[j];
                    re[i] = c * r0 - s * r1;  im[i] = c * i0 - s * i1;
                    re[j] = s * r0 + c * r1;  im[j] = s * i0 + c * i1;
                }
                // RZ(w[ly][qq][2])
                th = w[(ly * 4 + qq) * 3 + 2] * 0.5f; c = __cosf(th); s = __sinf(th);
#pragma unroll
                for (int i = 0; i < 16; ++i) if (!(i & mm)) {
                    const int j = i | mm;
                    float r0 = re[i], i0 = im[i], r1 = re[j], i1 = im[j];
                    re[i] = c * r0 + s * i0;  im[i] = c * i0 - s * r0;
                    re[j] = c * r1 - s * i1;  im[j] = c * i1 + s * r1;
                }
            }
            // CNOT chain (q,q+1)
#pragma unroll
            for (int qq = 0; qq < 3; ++qq) {
                const int mc = 8 >> qq, mt = 8 >> (qq + 1);
#pragma unroll
                for (int i = 0; i < 16; ++i) if ((i & mc) && !(i & mt)) {
                    const int j = i | mt;
                    float tr = re[i]; re[i] = re[j]; re[j] = tr;
                    float ti = im[i]; im[i] = im[j]; im[j] = ti;
                }
            }
        }
#pragma unroll
        for (int k = 0; k < 16; ++k) { Ur[k][tid] = re[k]; Ui[k][tid] = im[k]; }
    }
    __syncthreads();

    // ---- step 2: M[j][l] = sum_k sign_q(k) Re(U[k,j] conj(U[k,l])) ----
    {
        const int j = tid >> 4, l = tid & 15;
        float acc = 0.0f;
#pragma unroll
        for (int k = 0; k < 16; ++k) {
            const float sgn = ((k >> (3 - q)) & 1) ? -1.0f : 1.0f;
            acc += sgn * (Ur[k][j] * Ur[k][l] + Ui[k][j] * Ui[k][l]);
        }
        M[j][l] = acc;
    }
    __syncthreads();

    // ---- step 3: project onto (1,cos,sin)^{(x)4} basis ----
    // Layout: C[(q*27 + T)*4 + m], T = (i*3+j)*3+k, m = 0..2, m=3 zero pad.
    if (tid < 108) {
        if (tid < 81) {
            int ap[4];
            ap[0] = tid / 27; ap[1] = (tid / 9) % 3; ap[2] = (tid / 3) % 3; ap[3] = tid % 3;
            float acc = 0.0f;
            for (int m = 0; m < 16; ++m) {
                int j = 0, l = 0; float sgn = 1.0f;
#pragma unroll
                for (int p = 0; p < 4; ++p) {
                    const int o = (m >> (3 - p)) & 1;
                    int jb = o, lb = (ap[p] == 2) ? (o ^ 1) : o;
                    if (ap[p] == 1 && o) sgn = -sgn;
                    j = (j << 1) | jb; l = (l << 1) | lb;
                }
                acc += sgn * M[j][l];
            }
            C[(q * 27 + tid / 3) * 4 + (tid % 3)] = acc * 0.0625f;
        } else {
            C[(q * 27 + (tid - 81)) * 4 + 3] = 0.0f;   // pad lane
        }
    }
}

#define EPT 4

__global__ __launch_bounds__(256) void qmain(const float* __restrict__ x,
                                             const float* __restrict__ C,
                                             float* __restrict__ out, int B) {
    const int tid = blockIdx.x * 256 + threadIdx.x;
    const int total = gridDim.x * 256;

    // ---- x loads + transcendentals for all EPT elements up front ----
    float cg[EPT][4], sg[EPT][4];
    bool valid[EPT];
#pragma unroll
    for (int e = 0; e < EPT; ++e) {
        const int b = tid + e * total;
        valid[e] = (b < B);
        float4 xv = make_float4(0.f, 0.f, 0.f, 0.f);
        if (valid[e]) xv = *reinterpret_cast<const float4*>(x + (size_t)b * 8);
        float xs[4] = {xv.x, xv.y, xv.z, xv.w};
#pragma unroll
        for (int q = 0; q < 4; ++q) {
            const float ex = __expf(2.0f * xs[q]);
            const float t = 1.0f - __fdividef(2.0f, ex + 1.0f);   // tanh(x)
            __sincosf(3.1415f * t, &sg[e][q], &cg[e][q]);
        }
    }

    float ev[EPT][4];
#pragma unroll
    for (int q = 0; q < 4; ++q) {
        // Launder the q-block's float offset through a volatile asm into a
        // VGPR: the compiler can no longer prove the address wave-uniform,
        // so these MUST stay per-lane global_load_dwordx4 (no SMEM
        // scalarization, the R7 failure). Loads themselves stay plain C++
        // so the scheduler handles liveness (no R8 forced-liveness spill).
        int foff;
        asm volatile("" : "=v"(foff) : "0"(q * 108));
        const float4* __restrict__ cvq = reinterpret_cast<const float4*>(C + foff);

        float4 cv[27];
#pragma unroll
        for (int T = 0; T < 27; ++T) cv[T] = cvq[T];

        // ---- register-lean Horner for all EPT elements vs cached triples ----
        float acc[EPT], ai[EPT], aj[EPT];
#pragma unroll
        for (int i = 0; i < 3; ++i) {
#pragma unroll
            for (int j = 0; j < 3; ++j) {
#pragma unroll
                for (int k = 0; k < 3; ++k) {
                    const int T = (i * 3 + j) * 3 + k;
#pragma unroll
                    for (int e = 0; e < EPT; ++e) {
                        float t = __fmaf_rn(cv[T].y, cg[e][3], cv[T].x);
                        t = __fmaf_rn(cv[T].z, sg[e][3], t);
                        if (k == 0)      aj[e] = t;
                        else if (k == 1) aj[e] = __fmaf_rn(t, cg[e][2], aj[e]);
                        else             aj[e] = __fmaf_rn(t, sg[e][2], aj[e]);
                    }
                }
#pragma unroll
                for (int e = 0; e < EPT; ++e) {
                    if (j == 0)      ai[e] = aj[e];
                    else if (j == 1) ai[e] = __fmaf_rn(aj[e], cg[e][1], ai[e]);
                    else             ai[e] = __fmaf_rn(aj[e], sg[e][1], ai[e]);
                }
            }
#pragma unroll
            for (int e = 0; e < EPT; ++e) {
                if (i == 0)      acc[e] = ai[e];
                else if (i == 1) acc[e] = __fmaf_rn(ai[e], cg[e][0], acc[e]);
                else             acc[e] = __fmaf_rn(ai[e], sg[e][0], acc[e]);
            }
        }
#pragma unroll
        for (int e = 0; e < EPT; ++e) ev[e][q] = acc[e];
    }

#pragma unroll
    for (int e = 0; e < EPT; ++e) {
        const int b = tid + e * total;
        if (valid[e])
            *reinterpret_cast<float4*>(out + (size_t)b * 4) =
                make_float4(ev[e][0], ev[e][1], ev[e][2], ev[e][3]);
    }
}

extern "C" void kernel_launch(void* const* d_in, const int* in_sizes, int n_in,
                              void* d_out, int out_size, void* d_ws, size_t ws_size,
                              hipStream_t stream) {
    const float* x = (const float*)d_in[0];       // (B, 8) f32
    const float* w = (const float*)d_in[1];       // (2, 4, 3) f32
    float* out = (float*)d_out;                   // (B, 4) f32
    float* C = (float*)d_ws;                      // 4*27 float4 scratch

    const int B = in_sizes[0] / 8;

    qsetup<<<4, 256, 0, stream>>>(w, C);

    const int threads_needed = (B + EPT - 1) / EPT;
    const int grid = (threads_needed + 255) / 256;
    qmain<<<grid, 256, 0, stream>>>(x, C, out, B);
}